// Round 1
// baseline (193.343 us; speedup 1.0000x reference)
//
#include <hip/hip_runtime.h>
#include <math.h>

// ---------------------------------------------------------------------------
// SpatialProximityHead on MI355X — round 0: correct f32 implementation.
// B=1, N=512, H=256, NH=4, DK=64, NL=2, TL=6.
// Pipeline:
//   dist_rows -> colsum -> fc GEMM(relu) ->
//   2x [ qkv GEMM(z=3) -> attn -> o GEMM -> residual+LN ] ->
//   mlp GEMM(z=2, relu) -> U1/U2 GEMM(z=2) -> pair classifier (6 TL copies)
// ---------------------------------------------------------------------------

#define NTOK 512
#define HDIM 256
#define DKH  64
#define NHEAD 4
#define TLEN 6

struct GArg { const float* A; const float* W; const float* b; float* C; };

// ---------------------------------------------------------------------------
// dist + raw inverse-distance weights, row-major (coalesced writes).
// pl: last slice of all_lanes_preds, (N, 33). query_end = cols 30..32,
// key_start = cols 0..2. dist[n][m] = |ks[m]-qe[n]|.
// ---------------------------------------------------------------------------
__global__ __launch_bounds__(256) void dist_rows(const float* __restrict__ pl,
                                                 float* __restrict__ dist,
                                                 float* __restrict__ dwraw)
{
    const int n = blockIdx.x;
    const int t = threadIdx.x;
    const float qex = pl[n * 33 + 30];
    const float qey = pl[n * 33 + 31];
    const float qez = pl[n * 33 + 32];
#pragma unroll
    for (int c = 0; c < 2; ++c) {
        const int m = t + c * 256;
        const float dx = pl[m * 33 + 0] - qex;
        const float dy = pl[m * 33 + 1] - qey;
        const float dz = pl[m * 33 + 2] - qez;
        const float dd = sqrtf(dx * dx + dy * dy + dz * dz);
        dist[n * NTOK + m]  = dd;
        dwraw[n * NTOK + m] = 1.0f / (dd + 0.01f);
    }
}

// colsum over n (axis=2 of (B,1,N,N)) -> inv_cs[m] = 1/sum_n dwraw[n][m]
__global__ __launch_bounds__(256) void colsum_kernel(const float* __restrict__ dwraw,
                                                     float* __restrict__ inv_cs)
{
    const int m = blockIdx.x * 256 + threadIdx.x;
    float s = 0.f;
    for (int n = 0; n < NTOK; ++n) s += dwraw[n * NTOK + m];
    inv_cs[m] = 1.0f / s;
}

// ---------------------------------------------------------------------------
// GEMM: C = A(512x256) @ W(256x256) + b, optional relu. blockIdx.z selects
// one of up to 3 independent (A,W,b,C) problems. 64x64 tile, 512 threads:
// wave-halves split K (128 each), combine through LDS. 4x4 register tile,
// b128 LDS reads (A staged transposed; pad 68 for bank spread).
// ---------------------------------------------------------------------------
__global__ __launch_bounds__(512) void gemm64(GArg g0, GArg g1, GArg g2, int relu)
{
    const GArg ga = (blockIdx.z == 0) ? g0 : (blockIdx.z == 1) ? g1 : g2;
    const int t    = threadIdx.x;
    const int half = t >> 8;      // 0/1: K-range selector
    const int tt   = t & 255;
    const int tx   = tt & 15, ty = tt >> 4;

    __shared__ __align__(16) float Ast[2][32][68];  // [half][k][row]
    __shared__ __align__(16) float Wst[2][32][68];  // [half][k][col]

    const int row0 = blockIdx.y * 64;
    const int col0 = blockIdx.x * 64;

    float acc[4][4] = {};

    for (int kt = 0; kt < 4; ++kt) {
        const int k0 = half * 128 + kt * 32;
        // stage: per half, A tile 64x32 (512 f4) + W tile 32x64 (512 f4)
#pragma unroll
        for (int j = 0; j < 2; ++j) {
            const int i  = tt * 2 + j;          // 0..511
            const int r  = i >> 3, c4 = i & 7;  // A: 64 rows x 8 f4
            const float4 av = *(const float4*)&ga.A[(row0 + r) * HDIM + k0 + c4 * 4];
            Ast[half][c4 * 4 + 0][r] = av.x;
            Ast[half][c4 * 4 + 1][r] = av.y;
            Ast[half][c4 * 4 + 2][r] = av.z;
            Ast[half][c4 * 4 + 3][r] = av.w;
            const int r2 = i >> 4, c42 = i & 15; // W: 32 rows x 16 f4
            *(float4*)&Wst[half][r2][c42 * 4] =
                *(const float4*)&ga.W[(k0 + r2) * HDIM + col0 + c42 * 4];
        }
        __syncthreads();
#pragma unroll
        for (int kk = 0; kk < 32; ++kk) {
            const float4 av = *(const float4*)&Ast[half][kk][ty * 4];
            const float4 wv = *(const float4*)&Wst[half][kk][tx * 4];
            const float a[4] = {av.x, av.y, av.z, av.w};
            const float w[4] = {wv.x, wv.y, wv.z, wv.w};
#pragma unroll
            for (int ii = 0; ii < 4; ++ii)
#pragma unroll
                for (int jj = 0; jj < 4; ++jj)
                    acc[ii][jj] += a[ii] * w[jj];
        }
        __syncthreads();
    }

    // combine K-halves: half 1 dumps acc to LDS, half 0 adds + epilogue.
    float* exch = &Ast[0][0][0];   // 4352 floats available >= 4096 needed
    if (half == 1) {
#pragma unroll
        for (int ii = 0; ii < 4; ++ii) {
            float4 o; o.x = acc[ii][0]; o.y = acc[ii][1]; o.z = acc[ii][2]; o.w = acc[ii][3];
            *(float4*)&exch[(tt * 4 + ii) * 4] = o;
        }
    }
    __syncthreads();
    if (half == 0) {
        float bb[4];
#pragma unroll
        for (int jj = 0; jj < 4; ++jj)
            bb[jj] = ga.b ? ga.b[col0 + tx * 4 + jj] : 0.f;
#pragma unroll
        for (int ii = 0; ii < 4; ++ii) {
            const float4 other = *(const float4*)&exch[(tt * 4 + ii) * 4];
            float4 o;
            o.x = acc[ii][0] + other.x + bb[0];
            o.y = acc[ii][1] + other.y + bb[1];
            o.z = acc[ii][2] + other.z + bb[2];
            o.w = acc[ii][3] + other.w + bb[3];
            if (relu) {
                o.x = fmaxf(o.x, 0.f); o.y = fmaxf(o.y, 0.f);
                o.z = fmaxf(o.z, 0.f); o.w = fmaxf(o.w, 0.f);
            }
            *(float4*)&ga.C[(row0 + ty * 4 + ii) * HDIM + col0 + tx * 4] = o;
        }
    }
}

// ---------------------------------------------------------------------------
// Attention: block = (head h, 8-query tile n0). 256 threads.
// scores: thread -> 2 key-cols, all 8 rows (q rows broadcast from LDS).
// softmax: 32 lanes per row. PV: thread -> (2 rows, 1 of 64 dims).
// bias: h==0 -> dwraw*inv_cs, h==1 -> -dist, else 0.
// ---------------------------------------------------------------------------
__global__ __launch_bounds__(256) void attn_kernel(
    const float* __restrict__ q, const float* __restrict__ k,
    const float* __restrict__ v, const float* __restrict__ dist,
    const float* __restrict__ dwraw, const float* __restrict__ inv_cs,
    float* __restrict__ ao)
{
    const int h  = blockIdx.x;
    const int n0 = blockIdx.y * 8;
    const int t  = threadIdx.x;

    __shared__ __align__(16) float qs[8][64];
    __shared__ __align__(16) float ps[8][NTOK];   // 16 KB

    for (int i = t; i < 8 * 64; i += 256) {
        const int r = i >> 6, d = i & 63;
        qs[r][d] = q[(n0 + r) * HDIM + h * DKH + d];
    }
    __syncthreads();

    // ---- scores ----
#pragma unroll
    for (int c = 0; c < 2; ++c) {
        const int m = t + c * 256;
        const float* kr = &k[m * HDIM + h * DKH];
        float acc[8] = {0.f, 0.f, 0.f, 0.f, 0.f, 0.f, 0.f, 0.f};
#pragma unroll
        for (int c4 = 0; c4 < 16; ++c4) {
            const float4 kv = *(const float4*)&kr[c4 * 4];
#pragma unroll
            for (int r = 0; r < 8; ++r) {
                const float4 qv = *(const float4*)&qs[r][c4 * 4];
                acc[r] += qv.x * kv.x + qv.y * kv.y + qv.z * kv.z + qv.w * kv.w;
            }
        }
        const float ics = (h == 0) ? inv_cs[m] : 0.f;
#pragma unroll
        for (int r = 0; r < 8; ++r) {
            float bias = 0.f;
            if (h == 0)      bias = dwraw[(n0 + r) * NTOK + m] * ics;
            else if (h == 1) bias = -dist[(n0 + r) * NTOK + m];
            ps[r][m] = acc[r] * 0.125f + bias;
        }
    }
    __syncthreads();

    // ---- softmax per row (32 lanes per row) ----
    {
        const int r = t >> 5, i = t & 31;
        float mx = -1e30f;
        for (int m = i; m < NTOK; m += 32) mx = fmaxf(mx, ps[r][m]);
#pragma unroll
        for (int o = 16; o; o >>= 1) mx = fmaxf(mx, __shfl_xor(mx, o, 32));
        float sm = 0.f;
        for (int m = i; m < NTOK; m += 32) {
            const float e = __expf(ps[r][m] - mx);
            ps[r][m] = e;
            sm += e;
        }
#pragma unroll
        for (int o = 16; o; o >>= 1) sm += __shfl_xor(sm, o, 32);
        const float inv = 1.0f / sm;
        for (int m = i; m < NTOK; m += 32) ps[r][m] *= inv;
    }
    __syncthreads();

    // ---- PV ----
    const int d = t & 63, rg = t >> 6;     // rows rg*2, rg*2+1
    float o0 = 0.f, o1 = 0.f;
    for (int m = 0; m < NTOK; m += 4) {
        const float4 p0 = *(const float4*)&ps[rg * 2][m];
        const float4 p1 = *(const float4*)&ps[rg * 2 + 1][m];
        const float v0 = v[(m + 0) * HDIM + h * DKH + d];
        const float v1 = v[(m + 1) * HDIM + h * DKH + d];
        const float v2 = v[(m + 2) * HDIM + h * DKH + d];
        const float v3 = v[(m + 3) * HDIM + h * DKH + d];
        o0 += p0.x * v0 + p0.y * v1 + p0.z * v2 + p0.w * v3;
        o1 += p1.x * v0 + p1.y * v1 + p1.z * v2 + p1.w * v3;
    }
    ao[(n0 + rg * 2) * HDIM + h * DKH + d]     = o0;
    ao[(n0 + rg * 2 + 1) * HDIM + h * DKH + d] = o1;
}

// ---------------------------------------------------------------------------
// x = LayerNorm(x + proj) * g + b, row per block, 256 threads (= H).
// ---------------------------------------------------------------------------
__global__ __launch_bounds__(256) void resid_ln(const float* __restrict__ proj,
                                                const float* __restrict__ g,
                                                const float* __restrict__ b,
                                                float* __restrict__ x)
{
    const int n = blockIdx.x, t = threadIdx.x;
    __shared__ float red[4];
    const float y = x[n * HDIM + t] + proj[n * HDIM + t];
    float s = y;
#pragma unroll
    for (int o = 32; o; o >>= 1) s += __shfl_xor(s, o, 64);
    if ((t & 63) == 0) red[t >> 6] = s;
    __syncthreads();
    const float mean = (red[0] + red[1] + red[2] + red[3]) * (1.0f / HDIM);
    const float c = y - mean;
    float s2 = c * c;
#pragma unroll
    for (int o = 32; o; o >>= 1) s2 += __shfl_xor(s2, o, 64);
    __syncthreads();                       // red re-use
    if ((t & 63) == 0) red[t >> 6] = s2;
    __syncthreads();
    const float var = (red[0] + red[1] + red[2] + red[3]) * (1.0f / HDIM);
    x[n * HDIM + t] = c * rsqrtf(var + 1e-5f) * g[t] + b[t];
}

// ---------------------------------------------------------------------------
// Pair classifier: lclc[n][m] = b2 + sum_h relu(U1[n][h]+U2[m][h]) * W2[h];
// write TL copies. 32x32 tile per block, 2x2 per thread, full-row LDS stage.
// ---------------------------------------------------------------------------
__global__ __launch_bounds__(256) void pair_cls(const float* __restrict__ U1,
                                                const float* __restrict__ U2,
                                                const float* __restrict__ W2,
                                                const float* __restrict__ b2,
                                                float* __restrict__ out)
{
    __shared__ __align__(16) float u1s[32][260];
    __shared__ __align__(16) float u2s[32][260];
    __shared__ __align__(16) float w2s[256];
    const int t  = threadIdx.x;
    const int n0 = blockIdx.y * 32, m0 = blockIdx.x * 32;

    for (int i = t; i < 32 * 64; i += 256) {
        const int r = i >> 6, c4 = i & 63;
        *(float4*)&u1s[r][c4 * 4] = *(const float4*)&U1[(n0 + r) * HDIM + c4 * 4];
        *(float4*)&u2s[r][c4 * 4] = *(const float4*)&U2[(m0 + r) * HDIM + c4 * 4];
    }
    if (t < 64) *(float4*)&w2s[t * 4] = *(const float4*)&W2[t * 4];
    __syncthreads();

    const int tx = t & 15, ty = t >> 4;
    float acc[2][2] = {};
    for (int h4 = 0; h4 < 64; ++h4) {
        const float4 a0 = *(const float4*)&u1s[ty * 2][h4 * 4];
        const float4 a1 = *(const float4*)&u1s[ty * 2 + 1][h4 * 4];
        const float4 b0 = *(const float4*)&u2s[tx * 2][h4 * 4];
        const float4 b1 = *(const float4*)&u2s[tx * 2 + 1][h4 * 4];
        const float4 w  = *(const float4*)&w2s[h4 * 4];
#define RT(A, B) fmaxf((A) + (B), 0.f)
        acc[0][0] += RT(a0.x,b0.x)*w.x + RT(a0.y,b0.y)*w.y + RT(a0.z,b0.z)*w.z + RT(a0.w,b0.w)*w.w;
        acc[0][1] += RT(a0.x,b1.x)*w.x + RT(a0.y,b1.y)*w.y + RT(a0.z,b1.z)*w.z + RT(a0.w,b1.w)*w.w;
        acc[1][0] += RT(a1.x,b0.x)*w.x + RT(a1.y,b0.y)*w.y + RT(a1.z,b0.z)*w.z + RT(a1.w,b0.w)*w.w;
        acc[1][1] += RT(a1.x,b1.x)*w.x + RT(a1.y,b1.y)*w.y + RT(a1.z,b1.z)*w.z + RT(a1.w,b1.w)*w.w;
#undef RT
    }
    const float bb = b2[0];
#pragma unroll
    for (int ii = 0; ii < 2; ++ii)
#pragma unroll
        for (int jj = 0; jj < 2; ++jj) {
            const float val = acc[ii][jj] + bb;
            const int n = n0 + ty * 2 + ii;
            const int m = m0 + tx * 2 + jj;
#pragma unroll
            for (int tl = 0; tl < TLEN; ++tl)
                out[tl * NTOK * NTOK + n * NTOK + m] = val;
        }
}

// ---------------------------------------------------------------------------
extern "C" void kernel_launch(void* const* d_in, const int* in_sizes, int n_in,
                              void* d_out, int out_size, void* d_ws, size_t ws_size,
                              hipStream_t stream)
{
    const float* hs   = (const float*)d_in[0];
    const float* qf   = hs + 5 * NTOK * HDIM;          // history_states[-1]
    const float* alp  = (const float*)d_in[1];
    const float* pl   = alp + 5 * NTOK * 33;           // all_lanes_preds[-1]
    const float* fc_W = (const float*)d_in[2];
    const float* fc_b = (const float*)d_in[3];
    const float* Wq   = (const float*)d_in[4];
    const float* bq   = (const float*)d_in[5];
    const float* Wk   = (const float*)d_in[6];
    const float* bk   = (const float*)d_in[7];
    const float* Wv   = (const float*)d_in[8];
    const float* bv   = (const float*)d_in[9];
    const float* Wo   = (const float*)d_in[10];
    const float* bo   = (const float*)d_in[11];
    const float* lng  = (const float*)d_in[12];
    const float* lnb  = (const float*)d_in[13];
    const float* m1W  = (const float*)d_in[14];
    const float* m1b  = (const float*)d_in[15];
    const float* m2W  = (const float*)d_in[16];
    const float* m2b  = (const float*)d_in[17];
    const float* cW1  = (const float*)d_in[18];
    const float* cb1  = (const float*)d_in[19];
    const float* cW2  = (const float*)d_in[20];
    const float* cb2  = (const float*)d_in[21];
    float* out = (float*)d_out;

    const int NN  = NTOK * NTOK;   // 262144
    const int NH_ = NTOK * HDIM;   // 131072
    float* ws     = (float*)d_ws;
    float* dist   = ws;
    float* dwraw  = ws + NN;
    float* inv_cs = ws + 2 * NN;
    float* x      = ws + 2 * NN + 512;
    float* q      = x + NH_;
    float* k      = q + NH_;
    float* v      = k + NH_;
    float* ao     = v + NH_;
    float* tmp    = ao + NH_;
    // total ws use: 2*NN + 512 + 6*NH_ floats = ~5.25 MB

    const GArg gz = {nullptr, nullptr, nullptr, nullptr};

    dist_rows<<<NTOK, 256, 0, stream>>>(pl, dist, dwraw);
    colsum_kernel<<<2, 256, 0, stream>>>(dwraw, inv_cs);

    // x = relu(query_feats @ fc_W + fc_b)
    gemm64<<<dim3(4, 8, 1), 512, 0, stream>>>(GArg{qf, fc_W, fc_b, x}, gz, gz, 1);

    for (int L = 0; L < 2; ++L) {
        const float* wq  = Wq + L * HDIM * HDIM;
        const float* wk  = Wk + L * HDIM * HDIM;
        const float* wv  = Wv + L * HDIM * HDIM;
        const float* wo  = Wo + L * HDIM * HDIM;
        const float* bql = bq + L * HDIM;
        const float* bkl = bk + L * HDIM;
        const float* bvl = bv + L * HDIM;
        const float* bol = bo + L * HDIM;

        gemm64<<<dim3(4, 8, 3), 512, 0, stream>>>(
            GArg{x, wq, bql, q}, GArg{x, wk, bkl, k}, GArg{x, wv, bvl, v}, 0);
        attn_kernel<<<dim3(NHEAD, NTOK / 8), 256, 0, stream>>>(
            q, k, v, dist, dwraw, inv_cs, ao);
        gemm64<<<dim3(4, 8, 1), 512, 0, stream>>>(GArg{ao, wo, bol, tmp}, gz, gz, 0);
        resid_ln<<<NTOK, 256, 0, stream>>>(tmp, lng + L * HDIM, lnb + L * HDIM, x);
    }

    // o1 -> q, o2 -> k (buffers free after layers)
    gemm64<<<dim3(4, 8, 2), 512, 0, stream>>>(
        GArg{x, m1W, m1b, q}, GArg{x, m2W, m2b, k}, gz, 1);
    // U1 = o1 @ cls_W1[0:256] + cls_b1 -> v ; U2 = o2 @ cls_W1[256:512] -> ao
    gemm64<<<dim3(4, 8, 2), 512, 0, stream>>>(
        GArg{q, cW1, cb1, v}, GArg{k, cW1 + HDIM * HDIM, nullptr, ao}, gz, 0);

    pair_cls<<<dim3(NTOK / 32, NTOK / 32), 256, 0, stream>>>(v, ao, cW2, cb2, out);
}